// Round 2
// baseline (143.612 us; speedup 1.0000x reference)
//
#include <hip/hip_runtime.h>
#include <math.h>

namespace {
constexpr int Bc = 2, CINc = 3, Hc = 224, Wc = 224;
constexpr int COUTc = 64, KHc = 7, KWc = 7, SHc = 2, PADc = 3;
constexpr int MIXc = 4, RELc = 32;
constexpr int PHc = Hc + 2 * PADc, PWc = Wc + 2 * PADc;        // 230
constexpr int FHc = (PHc - KHc) / SHc + 1;                     // 112
constexpr int FWc = (PWc - KWc) / SHc + 1;                     // 112
constexpr int NN = FHc * FWc;                                  // 12544 = 49*256
constexpr int HWc = Hc * Wc;
constexpr int TS = 8;
// ws layout (floats):
constexpr int WS_EEX = 0;                    // [MIX][PW]
constexpr int WS_EEY = WS_EEX + MIXc * PWc;  // [MIX][PH]
constexpr int WS_RED = WS_EEY + MIXc * PHc;  // [B][49][2] = (max, denom)
}

// ---- K0: expEX[m][j] = exp(sum_c ex[c,j]*em[m,c]); expEY[m][i] likewise.
__global__ void sam_k0(const float* __restrict__ ex, const float* __restrict__ ey,
                       const float* __restrict__ em, float* __restrict__ ws) {
  const int idx = blockIdx.x * blockDim.x + threadIdx.x;
  constexpr int half = MIXc * PWc;
  if (idx >= 2 * half) return;
  const int which = idx >= half;
  const int r = which ? idx - half : idx;
  const int m = r / PWc;
  const int j = r % PWc;
  float s = 0.f;
  if (!which) {
#pragma unroll 8
    for (int c = 0; c < COUTc; ++c) s += ex[c * PWc + j] * em[m * COUTc + c];
  } else {
#pragma unroll 8
    for (int c = 0; c < COUTc; ++c) s += ey[c * PHc + j] * em[m * COUTc + c];
  }
  ws[idx] = expf(s);
}

// Collapsed-weight computation shared by K1/K2 (per-block, threads 0..50).
__device__ __forceinline__ void compute_collapsed(
    const float* __restrict__ wq, const float* __restrict__ wk,
    const float* __restrict__ rx, const float* __restrict__ ry,
    float (&sM)[3][3], float (&sRx)[3][KWc], float (&sRy)[3][KHc]) {
  const int t = threadIdx.x;
  if (t < 9) {
    const int cj = t / 3, ci = t % 3;
    float s = 0.f;
#pragma unroll 8
    for (int o = 0; o < COUTc; ++o) s += wq[cj * COUTc + o] * wk[ci * COUTc + o];
    sM[cj][ci] = s;
  } else if (t < 30) {
    const int u = t - 9; const int cj = u / KWc, kw = u % KWc;
    float s = 0.f;
#pragma unroll 8
    for (int o = 0; o < RELc; ++o) s += wq[cj * COUTc + o] * rx[o * KWc + kw];
    sRx[cj][kw] = s;
  } else if (t < 51) {
    const int u = t - 30; const int cj = u / KHc, kh = u % KHc;
    float s = 0.f;
#pragma unroll 8
    for (int o = 0; o < RELc; ++o) s += wq[cj * COUTc + RELc + o] * ry[o * KHc + kh];
    sRy[cj][kh] = s;
  }
}

__device__ __forceinline__ float blockReduce(float v, bool isMax, float* tmp) {
#pragma unroll
  for (int off = 32; off; off >>= 1) {
    const float o = __shfl_down(v, off, 64);
    v = isMax ? fmaxf(v, o) : (v + o);
  }
  __syncthreads();  // protect tmp from prior use
  if ((threadIdx.x & 63) == 0) tmp[threadIdx.x >> 6] = v;
  __syncthreads();
  float r = tmp[0];
#pragma unroll
  for (int i = 1; i < 4; ++i) r = isMax ? fmaxf(r, tmp[i]) : (r + tmp[i]);
  return r;
}

// ---- K1: one block per (k, b): global softmax stats over all NN positions.
__global__ __launch_bounds__(256) void sam_reduce(
    const float* __restrict__ x, const float* __restrict__ wq,
    const float* __restrict__ wk, const float* __restrict__ rx,
    const float* __restrict__ ry, float* __restrict__ ws) {
  __shared__ float sM[3][3], sRx[3][KWc], sRy[3][KHc];
  __shared__ float sc[NN];
  __shared__ float tmp[4];
  compute_collapsed(wq, wk, rx, ry, sM, sRx, sRy);
  __syncthreads();

  const int t = threadIdx.x;
  const int k = blockIdx.x, b = blockIdx.y;
  const int kh = k / KWc, kw = k % KWc;
  const float* xb = x + (size_t)b * CINc * HWc;
  const float rw0 = sRx[0][kw] + sRy[0][kh];
  const float rw1 = sRx[1][kw] + sRy[1][kh];
  const float rw2 = sRx[2][kw] + sRy[2][kh];

  float lmax = -3.0e38f;
#pragma unroll 1
  for (int n = t; n < NN; n += 256) {
    const int fh = n / FWc, fw = n - fh * FWc;
    const int i0 = fh * SHc, j0 = fw * SHc;
    const int co = i0 * Wc + j0;
    const float xc0 = xb[co], xc1 = xb[HWc + co], xc2 = xb[2 * HWc + co];
    float s = xc0 * rw0 + xc1 * rw1 + xc2 * rw2;
    const int ir = i0 + kh - PADc, jc = j0 + kw - PADc;
    if ((unsigned)ir < (unsigned)Hc && (unsigned)jc < (unsigned)Wc) {
      const float q0 = xc0 * sM[0][0] + xc1 * sM[1][0] + xc2 * sM[2][0];
      const float q1 = xc0 * sM[0][1] + xc1 * sM[1][1] + xc2 * sM[2][1];
      const float q2 = xc0 * sM[0][2] + xc1 * sM[1][2] + xc2 * sM[2][2];
      const int off = ir * Wc + jc;
      s += q0 * xb[off] + q1 * xb[HWc + off] + q2 * xb[2 * HWc + off];
    }
    sc[n] = s;
    lmax = fmaxf(lmax, s);
  }
  const float mx = blockReduce(lmax, true, tmp);
  float lsum = 0.f;
#pragma unroll 1
  for (int n = t; n < NN; n += 256) lsum += expf(sc[n] - mx);
  const float dn = blockReduce(lsum, false, tmp);
  if (t == 0) {
    ws[WS_RED + (b * (KHc * KWc) + k) * 2 + 0] = mx;
    ws[WS_RED + (b * (KHc * KWc) + k) * 2 + 1] = dn;
  }
}

// ---- K2: one thread per output pixel.
__global__ __launch_bounds__(64) void sam_k2(
    const float* __restrict__ x, const float* __restrict__ wq,
    const float* __restrict__ wk, const float* __restrict__ wv,
    const float* __restrict__ rx, const float* __restrict__ ry,
    const float* __restrict__ bias, const float* __restrict__ ws,
    float* __restrict__ out) {
  __shared__ float sM[3][3], sRx[3][KWc], sRy[3][KHc];
  __shared__ float smx[KHc * KWc], sdninv[KHc * KWc];
  compute_collapsed(wq, wk, rx, ry, sM, sRx, sRy);
  const int t = threadIdx.x;
  const int b = blockIdx.z;
  if (t >= 51 && t - 51 < KHc * KWc) {
    const int k = t - 51;  // threads 51..99 -> but blockDim=64, only k<13; loop below
  }
  // load softmax stats (49 entries) with the 64 threads
  if (t < KHc * KWc) {
    smx[t] = ws[WS_RED + (b * (KHc * KWc) + t) * 2 + 0];
    sdninv[t] = 1.f / ws[WS_RED + (b * (KHc * KWc) + t) * 2 + 1];
  }
  __syncthreads();

  const int fw = blockIdx.x * TS + (t & 7);
  const int fh = blockIdx.y * TS + (t >> 3);
  const int i0 = fh * SHc, j0 = fw * SHc;
  const float* xb = x + (size_t)b * CINc * HWc;

  float xc[3];
#pragma unroll
  for (int ci = 0; ci < 3; ++ci) xc[ci] = xb[ci * HWc + i0 * Wc + j0];

  float qk[3];
#pragma unroll
  for (int ci = 0; ci < 3; ++ci)
    qk[ci] = xc[0] * sM[0][ci] + xc[1] * sM[1][ci] + xc[2] * sM[2][ci];

  float rlx[KWc], rly[KHc];
#pragma unroll
  for (int kw = 0; kw < KWc; ++kw)
    rlx[kw] = xc[0] * sRx[0][kw] + xc[1] * sRx[1][kw] + xc[2] * sRx[2][kw];
#pragma unroll
  for (int kh = 0; kh < KHc; ++kh)
    rly[kh] = xc[0] * sRy[0][kh] + xc[1] * sRy[1][kh] + xc[2] * sRy[2][kh];

  // attention weights a_k = exp(s_k - max_k) / denom_k  (global softmax per k)
  float aarr[KHc * KWc];
#pragma unroll
  for (int kh = 0; kh < KHc; ++kh) {
    const int ir = i0 + kh - PADc;
    const bool rin = (unsigned)ir < (unsigned)Hc;
#pragma unroll
    for (int kw = 0; kw < KWc; ++kw) {
      const int jc = j0 + kw - PADc;
      float s = rlx[kw] + rly[kh];
      if (rin && ((unsigned)jc < (unsigned)Wc)) {
        const int off = ir * Wc + jc;
        s += qk[0] * xb[off] + qk[1] * xb[HWc + off] + qk[2] * xb[2 * HWc + off];
      }
      const int k = kh * KWc + kw;
      aarr[k] = expf(s - smx[k]) * sdninv[k];
    }
  }

  const float* eEX = ws + WS_EEX;
  const float* eEY = ws + WS_EEY;

  float T[MIXc][3] = {{0.f}};
#pragma unroll
  for (int kh = 0; kh < KHc; ++kh) {
    const int i = i0 + kh;
    const int ir = i - PADc;
    if ((unsigned)ir >= (unsigned)Hc) continue;
    const float ey0 = eEY[0 * PHc + i], ey1 = eEY[1 * PHc + i];
    const float ey2 = eEY[2 * PHc + i], ey3 = eEY[3 * PHc + i];
#pragma unroll
    for (int kw = 0; kw < KWc; ++kw) {
      const int j = j0 + kw;
      const int jc = j - PADc;
      if ((unsigned)jc >= (unsigned)Wc) continue;
      const float e0 = eEX[0 * PWc + j] * ey0;
      const float e1 = eEX[1 * PWc + j] * ey1;
      const float e2 = eEX[2 * PWc + j] * ey2;
      const float e3 = eEX[3 * PWc + j] * ey3;
      const float w = aarr[kh * KWc + kw] / (e0 + e1 + e2 + e3);
      const int off = ir * Wc + jc;
      const float x0 = xb[off], x1 = xb[HWc + off], x2 = xb[2 * HWc + off];
      const float a0 = w * e0, a1 = w * e1, a2 = w * e2, a3 = w * e3;
      T[0][0] += a0 * x0; T[0][1] += a0 * x1; T[0][2] += a0 * x2;
      T[1][0] += a1 * x0; T[1][1] += a1 * x1; T[1][2] += a1 * x2;
      T[2][0] += a2 * x0; T[2][1] += a2 * x1; T[2][2] += a2 * x2;
      T[3][0] += a3 * x0; T[3][1] += a3 * x1; T[3][2] += a3 * x2;
    }
  }

  float* ob = out + ((size_t)b * COUTc) * NN + fh * FWc + fw;
#pragma unroll 4
  for (int o = 0; o < COUTc; ++o) {
    float acc = bias[o];
#pragma unroll
    for (int m = 0; m < MIXc; ++m)
#pragma unroll
      for (int ci = 0; ci < 3; ++ci)
        acc += wv[(m * 3 + ci) * COUTc + o] * T[m][ci];
    ob[(size_t)o * NN] = acc;
  }
}

extern "C" void kernel_launch(void* const* d_in, const int* in_sizes, int n_in,
                              void* d_out, int out_size, void* d_ws, size_t ws_size,
                              hipStream_t stream) {
  const float* x    = (const float*)d_in[0];
  const float* wq   = (const float*)d_in[1];
  const float* wk   = (const float*)d_in[2];
  const float* wv   = (const float*)d_in[3];
  const float* rx   = (const float*)d_in[4];
  const float* ry   = (const float*)d_in[5];
  const float* ex   = (const float*)d_in[6];
  const float* ey   = (const float*)d_in[7];
  const float* em   = (const float*)d_in[8];
  const float* bias = (const float*)d_in[9];
  float* out = (float*)d_out;
  float* ws  = (float*)d_ws;

  sam_k0<<<dim3((2 * MIXc * PWc + 255) / 256), 256, 0, stream>>>(ex, ey, em, ws);
  sam_reduce<<<dim3(KHc * KWc, Bc), 256, 0, stream>>>(x, wq, wk, rx, ry, ws);
  sam_k2<<<dim3(FWc / TS, FHc / TS, Bc), 64, 0, stream>>>(x, wq, wk, wv, rx, ry, bias, ws, out);
}

// Round 4
// 102.367 us; speedup vs baseline: 1.4029x; 1.4029x over previous
//
#include <hip/hip_runtime.h>
#include <math.h>

namespace {
constexpr int Bc = 2, Hc = 224, Wc = 224, HWc = Hc * Wc;
constexpr int COUTc = 64, KHc = 7, KWc = 7, PADc = 3;
constexpr int MIXc = 4, RELc = 32;
constexpr int PHc = 230, PWc = 230;
constexpr int FHc = 112, FWc = 112, NN = FHc * FWc;   // 12544 = 196*64
constexpr int NK = KHc * KWc;                         // 49
// ws float offsets
constexpr int WS_EEX = 0;                             // [4][230] exp(ex.em)
constexpr int WS_EEY = WS_EEX + MIXc * PWc;           // [4][230] exp(ey.em)
constexpr int WS_COL = WS_EEY + MIXc * PHc;           // M[9], Rx[21], Ry[21]
constexpr int WS_ACC = 1920;                          // [B][49] slots, 16-float (64B) padded
}

// ---- K0: mixture-softmax tables + collapsed weights + zero accumulators.
__global__ __launch_bounds__(256) void sam_k0(
    const float* __restrict__ ex, const float* __restrict__ ey,
    const float* __restrict__ em, const float* __restrict__ wq,
    const float* __restrict__ wk, const float* __restrict__ rx,
    const float* __restrict__ ry, float* __restrict__ ws) {
  const int idx = blockIdx.x * 256 + threadIdx.x;
  if (idx < Bc * NK) ws[WS_ACC + idx * 16] = 0.f;  // zero softmax denominators

  constexpr int half = MIXc * PWc;
  if (idx < 2 * half) {
    const int which = idx >= half;
    const int r = which ? idx - half : idx;
    const int m = r / PWc, j = r % PWc;
    float s = 0.f;
#pragma unroll 8
    for (int c = 0; c < COUTc; ++c)
      s += (which ? ey[c * PHc + j] : ex[c * PWc + j]) * em[m * COUTc + c];
    ws[idx] = expf(s);
  }

  const int u = idx - 2 * half;
  if (u >= 0 && u < 51) {
    float s = 0.f;
    if (u < 9) {                      // M[cj*3+ci] = sum_o wq[cj,o]*wk[ci,o]
      const int cj = u / 3, ci = u % 3;
#pragma unroll 8
      for (int o = 0; o < COUTc; ++o) s += wq[cj * COUTc + o] * wk[ci * COUTc + o];
    } else if (u < 30) {              // Rx[cj*7+kw] = sum_{o<32} wq[cj,o]*rx[o,kw]
      const int v = u - 9, cj = v / 7, kw = v % 7;
#pragma unroll 8
      for (int o = 0; o < RELc; ++o) s += wq[cj * COUTc + o] * rx[o * KWc + kw];
    } else {                          // Ry[cj*7+kh] = sum_{o<32} wq[cj,32+o]*ry[o,kh]
      const int v = u - 30, cj = v / 7, kh = v % 7;
#pragma unroll 8
      for (int o = 0; o < RELc; ++o) s += wq[cj * COUTc + RELc + o] * ry[o * KHc + kh];
    }
    ws[WS_COL + u] = s;
  }
}

// ---- K1: global-softmax denominators. One wave = one k over 64 positions.
// grid (NN/64=196, ceil(49/4)=13, B), block 256.
__global__ __launch_bounds__(256) void sam_stats(const float* __restrict__ x,
                                                 float* __restrict__ ws) {
  __shared__ float sCol[51];
  const int t = threadIdx.x;
  if (t < 51) sCol[t] = ws[WS_COL + t];
  __syncthreads();

  const int w = t >> 6, lane = t & 63;
  const int k = blockIdx.y * 4 + w;
  if (k >= NK) return;
  const int b = blockIdx.z;
  const int kh = k / 7, kw = k - 7 * kh;
  const int n = blockIdx.x * 64 + lane;
  const int fh = n / FWc, fw = n - fh * FWc;
  const int i0 = 2 * fh, j0 = 2 * fw;
  const float* xb = x + (size_t)b * 3 * HWc;
  const int co = i0 * Wc + j0;
  const float xc0 = xb[co], xc1 = xb[HWc + co], xc2 = xb[2 * HWc + co];
  const float* M = sCol;
  const float* Rx = sCol + 9;
  const float* Ry = sCol + 30;

  float s = xc0 * (Rx[kw] + Ry[kh]) + xc1 * (Rx[7 + kw] + Ry[7 + kh]) +
            xc2 * (Rx[14 + kw] + Ry[14 + kh]);
  const int ir = i0 + kh - PADc, jc = j0 + kw - PADc;
  if ((unsigned)ir < (unsigned)Hc && (unsigned)jc < (unsigned)Wc) {
    const float q0 = xc0 * M[0] + xc1 * M[3] + xc2 * M[6];
    const float q1 = xc0 * M[1] + xc1 * M[4] + xc2 * M[7];
    const float q2 = xc0 * M[2] + xc1 * M[5] + xc2 * M[8];
    const int off = ir * Wc + jc;
    s += q0 * xb[off] + q1 * xb[HWc + off] + q2 * xb[2 * HWc + off];
  }
  float e = expf(s);
#pragma unroll
  for (int m2 = 32; m2; m2 >>= 1) e += __shfl_xor(e, m2, 64);
  if (lane == 0) atomicAdd(ws + WS_ACC + ((size_t)b * NK + k) * 16, e);
}

// ---- K2: output. Block = 512 threads = 64 pixels x 8 tap-groups.
// grid (NN/64=196, B).
__global__ __launch_bounds__(512) void sam_out(
    const float* __restrict__ x, const float* __restrict__ wv,
    const float* __restrict__ bias, const float* __restrict__ ws,
    float* __restrict__ out) {
  __shared__ float sCol[51];
  __shared__ float sdninv[NK];
  __shared__ float swv[12 * 64];
  __shared__ float sbias[64];
  __shared__ float sT[8][64][13];  // stride 13 -> conflict-light

  const int t = threadIdx.x;
  const int b = blockIdx.y;
  if (t < 51) sCol[t] = ws[WS_COL + t];
  if (t < NK) sdninv[t] = 1.f / ws[WS_ACC + ((size_t)b * NK + t) * 16];
  if (t < 64) sbias[t] = bias[t];
  for (int i = t; i < 12 * 64; i += 512) swv[i] = wv[i];
  __syncthreads();

  const int w = t >> 6, l = t & 63;
  const int n = blockIdx.x * 64 + l;
  const int fh = n / FWc, fw = n - fh * FWc;
  const int i0 = 2 * fh, j0 = 2 * fw;
  const float* xb = x + (size_t)b * 3 * HWc;
  const int co = i0 * Wc + j0;
  const float xc0 = xb[co], xc1 = xb[HWc + co], xc2 = xb[2 * HWc + co];
  const float* M = sCol;
  const float* Rx = sCol + 9;
  const float* Ry = sCol + 30;
  const float q0 = xc0 * M[0] + xc1 * M[3] + xc2 * M[6];
  const float q1 = xc0 * M[1] + xc1 * M[4] + xc2 * M[7];
  const float q2 = xc0 * M[2] + xc1 * M[5] + xc2 * M[8];
  float rlx[7], rly[7];
#pragma unroll
  for (int kw = 0; kw < 7; ++kw)
    rlx[kw] = xc0 * Rx[kw] + xc1 * Rx[7 + kw] + xc2 * Rx[14 + kw];
#pragma unroll
  for (int kh = 0; kh < 7; ++kh)
    rly[kh] = xc0 * Ry[kh] + xc1 * Ry[7 + kh] + xc2 * Ry[14 + kh];

  const float* eEX = ws + WS_EEX;
  const float* eEY = ws + WS_EEY;

  float T[12] = {0.f};  // [m*3+ci]
#pragma unroll 1
  for (int kk = w; kk < NK; kk += 8) {
    const int kh = kk / 7, kw = kk - 7 * kh;
    const int ir = i0 + kh - PADc, jc = j0 + kw - PADc;
    if ((unsigned)ir >= (unsigned)Hc || (unsigned)jc >= (unsigned)Wc) continue;
    float s = rlx[kw] + rly[kh];
    const int off = ir * Wc + jc;
    const float x0 = xb[off], x1 = xb[HWc + off], x2 = xb[2 * HWc + off];
    s += q0 * x0 + q1 * x1 + q2 * x2;
    const float e = expf(s) * sdninv[kk];
    const int ii = i0 + kh, jj = j0 + kw;
    const float p0 = eEX[jj] * eEY[ii];
    const float p1 = eEX[PWc + jj] * eEY[PHc + ii];
    const float p2 = eEX[2 * PWc + jj] * eEY[2 * PHc + ii];
    const float p3 = eEX[3 * PWc + jj] * eEY[3 * PHc + ii];
    const float wgt = e / (p0 + p1 + p2 + p3);
    const float a0 = wgt * p0, a1 = wgt * p1, a2 = wgt * p2, a3 = wgt * p3;
    T[0] += a0 * x0; T[1]  += a0 * x1; T[2]  += a0 * x2;
    T[3] += a1 * x0; T[4]  += a1 * x1; T[5]  += a1 * x2;
    T[6] += a2 * x0; T[7]  += a2 * x1; T[8]  += a2 * x2;
    T[9] += a3 * x0; T[10] += a3 * x1; T[11] += a3 * x2;
  }
#pragma unroll
  for (int j = 0; j < 12; ++j) sT[w][l][j] = T[j];
  __syncthreads();

  // Reduce 8 partials and project to 64 output channels (8 o's per thread).
  float Tm[12];
#pragma unroll
  for (int j = 0; j < 12; ++j) {
    float s = 0.f;
#pragma unroll
    for (int ww = 0; ww < 8; ++ww) s += sT[ww][l][j];
    Tm[j] = s;
  }
  float* ob = out + (size_t)b * COUTc * NN + n;
#pragma unroll
  for (int oo = 0; oo < 8; ++oo) {
    const int o = w * 8 + oo;
    float acc = sbias[o];
#pragma unroll
    for (int mc = 0; mc < 12; ++mc) acc += swv[mc * 64 + o] * Tm[mc];
    ob[(size_t)o * NN] = acc;
  }
}

extern "C" void kernel_launch(void* const* d_in, const int* in_sizes, int n_in,
                              void* d_out, int out_size, void* d_ws, size_t ws_size,
                              hipStream_t stream) {
  const float* x    = (const float*)d_in[0];
  const float* wq   = (const float*)d_in[1];
  const float* wk   = (const float*)d_in[2];
  const float* wv   = (const float*)d_in[3];
  const float* rx   = (const float*)d_in[4];
  const float* ry   = (const float*)d_in[5];
  const float* ex   = (const float*)d_in[6];
  const float* ey   = (const float*)d_in[7];
  const float* em   = (const float*)d_in[8];
  const float* bias = (const float*)d_in[9];
  float* out = (float*)d_out;
  float* ws  = (float*)d_ws;

  sam_k0<<<dim3(8), 256, 0, stream>>>(ex, ey, em, wq, wk, rx, ry, ws);
  sam_stats<<<dim3(NN / 64, (NK + 3) / 4, Bc), 256, 0, stream>>>(x, ws);
  sam_out<<<dim3(NN / 64, Bc), 512, 0, stream>>>(x, wv, bias, ws, out);
}